// Round 1
// baseline (90.179 us; speedup 1.0000x reference)
//
#include <hip/hip_runtime.h>

#define EPSF 0.01f
#define THREADS 256
#define ITEMS 16
#define TILE (THREADS * ITEMS)   // 4096 elements per tile
#define NBMAX 1024

// Compute the 5 per-category change scalars exactly as the reference does.
// jnp.clip(x, lo, hi) == min(max(x, lo), hi)
__device__ __forceinline__ void load_changes(const float* bd, const float* de,
                                             const float* sa, const float* in,
                                             const float* bi, float ch[5]) {
    float vbd = *bd, vd = *de, vs = *sa, vi = *in, vbi = *bi;
    ch[0] = fminf(vbd, fminf(0.0f, vd) - EPSF);
    ch[1] = fminf(fmaxf(vd, vbd + EPSF), 0.0f - EPSF);
    ch[2] = fminf(fmaxf(vs, vd + EPSF), vi - EPSF);
    ch[3] = fminf(fmaxf(vi, 0.0f + EPSF), vbi - EPSF);
    ch[4] = fmaxf(vbi, fmaxf(0.0f, vi) + EPSF);
}

__device__ __forceinline__ float sel_change(int v, float c0, float c1, float c2,
                                            float c3, float c4) {
    // cmp+cndmask chain; avoids runtime-indexed array (scratch) and LDS table
    // (bank conflicts).
    return (v == 1) ? c0 : (v == 2) ? c1 : (v == 3) ? c2 : (v == 4) ? c3 : c4;
}

// Pass 1: per-block category counts. Packed uint64 accumulator, 12-bit fields
// (per-thread element count = chunk/1024 <= 4095 for chunk <= ~1M; here 128).
__global__ __launch_bounds__(THREADS) void k_count(const int* __restrict__ ann,
                                                   int* __restrict__ bc,
                                                   long long n, long long chunk) {
    long long start = (long long)blockIdx.x * chunk;
    long long end = start + chunk;
    if (end > n) end = n;

    unsigned long long pk = 0ull;
    long long i = start + (long long)threadIdx.x * 4;
    const long long stride = (long long)blockDim.x * 4;
    for (; i + 3 < end; i += stride) {
        int4 a = *reinterpret_cast<const int4*>(ann + i);
        pk += (1ull << ((a.x - 1) * 12));
        pk += (1ull << ((a.y - 1) * 12));
        pk += (1ull << ((a.z - 1) * 12));
        pk += (1ull << ((a.w - 1) * 12));
    }
    if (i < end) {  // loop exit guarantees end <= i+3, so this covers <=4 elems, disjoint per thread
        for (long long j = i; j < end; ++j) pk += (1ull << ((ann[j] - 1) * 12));
    }

    int cnt[5];
#pragma unroll
    for (int c = 0; c < 5; ++c) cnt[c] = (int)((pk >> (c * 12)) & 0xFFFull);

    int lane = threadIdx.x & 63, wv = threadIdx.x >> 6;
#pragma unroll
    for (int c = 0; c < 5; ++c) {
        int x = cnt[c];
#pragma unroll
        for (int off = 32; off > 0; off >>= 1) x += __shfl_down(x, off, 64);
        cnt[c] = x;  // lane 0 holds wave total
    }
    __shared__ int sred[THREADS / 64][5];
    if (lane == 0) {
#pragma unroll
        for (int c = 0; c < 5; ++c) sred[wv][c] = cnt[c];
    }
    __syncthreads();
    if (threadIdx.x == 0) {
#pragma unroll
        for (int c = 0; c < 5; ++c)
            bc[blockIdx.x * 5 + c] =
                sred[0][c] + sred[1][c] + sred[2][c] + sred[3][c];
    }
}

// Pass 2: exclusive scan of per-block counts (exact integers), convert to
// per-block float base offsets: origin + sum_c excl_count_c * change_c.
__global__ __launch_bounds__(NBMAX) void k_scan(const int* __restrict__ bc,
                                                float* __restrict__ bb, int nb,
                                                const float* org, const float* bd,
                                                const float* de, const float* sa,
                                                const float* in, const float* bi) {
    __shared__ int buf[NBMAX];
    float ch[5];
    load_changes(bd, de, sa, in, bi, ch);
    int t = threadIdx.x;
    double acc = (double)(*org);
#pragma unroll
    for (int c = 0; c < 5; ++c) {
        int v = (t < nb) ? bc[t * 5 + c] : 0;
        int x = v;
        buf[t] = x;
        __syncthreads();
        for (int off = 1; off < NBMAX; off <<= 1) {
            int y = (t >= off) ? buf[t - off] : 0;
            __syncthreads();
            x += y;
            buf[t] = x;
            __syncthreads();
        }
        acc += (double)(x - v) * (double)ch[c];  // exclusive = inclusive - own
        __syncthreads();
    }
    if (t < nb) bb[t] = (float)acc;
}

// Pass 3: emit out[o] = origin + exclusive_prefix(step, o) for o in [0, n];
// exclusive form keeps every float4 store 16B-aligned (out[0]=origin falls out
// naturally; out[n] written by the block that owns the end).
__global__ __launch_bounds__(THREADS) void k_emit(const int* __restrict__ ann,
                                                  const float* __restrict__ bb,
                                                  float* __restrict__ out,
                                                  long long n, long long chunk,
                                                  const float* bd, const float* de,
                                                  const float* sa, const float* in,
                                                  const float* bi) {
    float ch[5];
    load_changes(bd, de, sa, in, bi, ch);
    const float c0 = ch[0], c1 = ch[1], c2 = ch[2], c3 = ch[3], c4 = ch[4];

    __shared__ float wsum[THREADS / 64];
    long long start = (long long)blockIdx.x * chunk;
    long long end = start + chunk;
    if (end > n) end = n;
    float running = bb[blockIdx.x];
    const int lane = threadIdx.x & 63, wv = threadIdx.x >> 6;

    for (long long ts = start; ts < end; ts += TILE) {
        long long i0 = ts + (long long)threadIdx.x * ITEMS;
        float e[ITEMS + 1];
        e[0] = 0.0f;
        const bool full = (ts + TILE <= n);
        if (full) {
            const int4* p = reinterpret_cast<const int4*>(ann + i0);
            int4 a0 = p[0], a1 = p[1], a2 = p[2], a3 = p[3];
            int vv[ITEMS] = {a0.x, a0.y, a0.z, a0.w, a1.x, a1.y, a1.z, a1.w,
                             a2.x, a2.y, a2.z, a2.w, a3.x, a3.y, a3.z, a3.w};
#pragma unroll
            for (int j = 0; j < ITEMS; ++j)
                e[j + 1] = e[j] + sel_change(vv[j], c0, c1, c2, c3, c4);
        } else {
#pragma unroll
            for (int j = 0; j < ITEMS; ++j) {
                float cv = 0.0f;
                if (i0 + j < n) cv = sel_change(ann[i0 + j], c0, c1, c2, c3, c4);
                e[j + 1] = e[j] + cv;
            }
        }
        float lsum = e[ITEMS];

        // block exclusive scan of per-thread sums
        float x = lsum;
#pragma unroll
        for (int off = 1; off < 64; off <<= 1) {
            float y = __shfl_up(x, off, 64);
            if (lane >= off) x += y;
        }
        if (lane == 63) wsum[wv] = x;
        __syncthreads();
        float w0 = wsum[0], w1 = wsum[1], w2 = wsum[2], w3 = wsum[3];
        float waveOff = (wv > 0 ? w0 : 0.0f) + (wv > 1 ? w1 : 0.0f) +
                        (wv > 2 ? w2 : 0.0f);
        float total = w0 + w1 + w2 + w3;
        __syncthreads();  // wsum reusable next tile

        float base = running + waveOff + (x - lsum);
        if (full) {
            float4* q = reinterpret_cast<float4*>(out + i0);
            q[0] = make_float4(base + e[0], base + e[1], base + e[2], base + e[3]);
            q[1] = make_float4(base + e[4], base + e[5], base + e[6], base + e[7]);
            q[2] = make_float4(base + e[8], base + e[9], base + e[10], base + e[11]);
            q[3] = make_float4(base + e[12], base + e[13], base + e[14], base + e[15]);
        } else {
#pragma unroll
            for (int j = 0; j < ITEMS; ++j)
                if (i0 + j < n) out[i0 + j] = base + e[j];
        }
        running += total;
    }
    if (end == n && threadIdx.x == 0) out[n] = running;  // inclusive total
}

extern "C" void kernel_launch(void* const* d_in, const int* in_sizes, int n_in,
                              void* d_out, int out_size, void* d_ws, size_t ws_size,
                              hipStream_t stream) {
    const int* ann = (const int*)d_in[0];
    const float* org = (const float*)d_in[1];
    const float* bd = (const float*)d_in[2];
    const float* de = (const float*)d_in[3];
    const float* sa = (const float*)d_in[4];
    const float* in = (const float*)d_in[5];
    const float* bi = (const float*)d_in[6];
    float* out = (float*)d_out;

    long long n = (long long)in_sizes[0];
    long long nTiles = (n + TILE - 1) / TILE;
    long long tpb = (nTiles + NBMAX - 1) / NBMAX;   // tiles per block
    if (tpb < 1) tpb = 1;
    long long chunk = tpb * TILE;
    int nb = (int)((n + chunk - 1) / chunk);
    if (nb < 1) nb = 1;

    int* bc = (int*)d_ws;                    // nb*5 ints
    float* bb = (float*)(bc + NBMAX * 5);    // nb floats (fixed offset)

    k_count<<<nb, THREADS, 0, stream>>>(ann, bc, n, chunk);
    k_scan<<<1, NBMAX, 0, stream>>>(bc, bb, nb, org, bd, de, sa, in, bi);
    k_emit<<<nb, THREADS, 0, stream>>>(ann, bb, out, n, chunk, bd, de, sa, in, bi);
}